// Round 1
// baseline (188.292 us; speedup 1.0000x reference)
//
#include <hip/hip_runtime.h>

#define N_TASKS 8
#define N_ROBOTS 3
#define ROW 24  // N_TASKS * N_ROBOTS

// ---------------------------------------------------------------------------
// Stage 1: per-block partial sums of (base_loss terms, capability_violation
// terms), written as doubles to d_ws:
//   ws[blockIdx]             = sum of softplus(p)-p*t over this block's rows
//   ws[gridDim + blockIdx]   = sum of capability shortage over this block's rows
// Deterministic: fixed row->thread partition, fixed reduction tree.
// ---------------------------------------------------------------------------
__global__ __launch_bounds__(256) void mrta_partial_kernel(
    const float* __restrict__ pred,
    const float* __restrict__ targ,
    const float* __restrict__ Rm,
    const float* __restrict__ Qm,
    double* __restrict__ partials,
    int B)
{
    const int tid      = blockIdx.x * blockDim.x + threadIdx.x;
    const int nthreads = gridDim.x * blockDim.x;

    double base_acc = 0.0;
    double cap_acc  = 0.0;

    for (int b = tid; b < B; b += nthreads) {
        float p[ROW], t[ROW], r[ROW];
        {
            const float4* pv = reinterpret_cast<const float4*>(pred + (size_t)b * ROW);
            const float4* tv = reinterpret_cast<const float4*>(targ + (size_t)b * ROW);
            const float4* rv = reinterpret_cast<const float4*>(Rm   + (size_t)b * ROW);
#pragma unroll
            for (int i = 0; i < 6; ++i) {
                float4 x = pv[i];
                p[4*i+0] = x.x; p[4*i+1] = x.y; p[4*i+2] = x.z; p[4*i+3] = x.w;
            }
#pragma unroll
            for (int i = 0; i < 6; ++i) {
                float4 x = tv[i];
                t[4*i+0] = x.x; t[4*i+1] = x.y; t[4*i+2] = x.z; t[4*i+3] = x.w;
            }
#pragma unroll
            for (int i = 0; i < 6; ++i) {
                float4 x = rv[i];
                r[4*i+0] = x.x; r[4*i+1] = x.y; r[4*i+2] = x.z; r[4*i+3] = x.w;
            }
        }

        // ---- BCE-with-logits partial: softplus(x) - x*t (stable softplus)
        float base = 0.0f;
#pragma unroll
        for (int i = 0; i < ROW; ++i) {
            float x  = p[i];
            float sp = fmaxf(x, 0.0f) + log1pf(expf(-fabsf(x)));
            base += sp - x * t[i];
        }

        // ---- capability violation
        float q[9];
        {
            const float* qp = Qm + (size_t)b * 9;
#pragma unroll
            for (int i = 0; i < 9; ++i) q[i] = qp[i];
        }

        float cap = 0.0f;
#pragma unroll
        for (int tk = 0; tk < N_TASKS; ++tk) {
            float p0 = p[tk*3 + 0];
            float p1 = p[tk*3 + 1];
            float p2 = p[tk*3 + 2];
            float a0 = (p0 > 0.5f) ? 1.0f : 0.0f;
            float a1 = (p1 > 0.5f) ? 1.0f : 0.0f;
            float a2 = (p2 > 0.5f) ? 1.0f : 0.0f;
            // total_capability[c] = sum_r assigned[r] * Q[r][c]
            float tc0 = a0 * q[0] + a1 * q[3] + a2 * q[6];
            float tc1 = a0 * q[1] + a1 * q[4] + a2 * q[7];
            float tc2 = a0 * q[2] + a1 * q[5] + a2 * q[8];
            float sh  = fmaxf(r[tk*3 + 0] - tc0, 0.0f)
                      + fmaxf(r[tk*3 + 1] - tc1, 0.0f)
                      + fmaxf(r[tk*3 + 2] - tc2, 0.0f);
            bool active = (p0 + p1 + p2) > 0.0f;
            cap += active ? sh : 0.0f;
        }

        base_acc += (double)base;
        cap_acc  += (double)cap;
    }

    // ---- wave (64-lane) reduction
#pragma unroll
    for (int off = 32; off > 0; off >>= 1) {
        base_acc += __shfl_down(base_acc, off);
        cap_acc  += __shfl_down(cap_acc, off);
    }

    __shared__ double sbase[4];
    __shared__ double scap[4];
    const int wave = threadIdx.x >> 6;
    const int lane = threadIdx.x & 63;
    if (lane == 0) { sbase[wave] = base_acc; scap[wave] = cap_acc; }
    __syncthreads();
    if (threadIdx.x == 0) {
        double bsum = sbase[0] + sbase[1] + sbase[2] + sbase[3];
        double csum = scap[0]  + scap[1]  + scap[2]  + scap[3];
        partials[blockIdx.x]             = bsum;
        partials[gridDim.x + blockIdx.x] = csum;
    }
}

// ---------------------------------------------------------------------------
// Stage 2: single-block deterministic reduction of the block partials and
// final scalar math. out = {total_loss, base_loss, cap_violation, 0}
// ---------------------------------------------------------------------------
__global__ __launch_bounds__(256) void mrta_final_kernel(
    const double* __restrict__ partials,
    int nparts,
    float* __restrict__ out,
    double inv_BM,   // 1 / (B * 24)
    double inv_B)    // 1 / B
{
    double b = 0.0, c = 0.0;
    for (int i = threadIdx.x; i < nparts; i += 256) {
        b += partials[i];
        c += partials[nparts + i];
    }
#pragma unroll
    for (int off = 32; off > 0; off >>= 1) {
        b += __shfl_down(b, off);
        c += __shfl_down(c, off);
    }
    __shared__ double sb[4];
    __shared__ double sc[4];
    const int wave = threadIdx.x >> 6;
    const int lane = threadIdx.x & 63;
    if (lane == 0) { sb[wave] = b; sc[wave] = c; }
    __syncthreads();
    if (threadIdx.x == 0) {
        double bsum = sb[0] + sb[1] + sb[2] + sb[3];
        double csum = sc[0] + sc[1] + sc[2] + sc[3];
        double base = bsum * inv_BM;
        double cap  = csum * inv_B;
        double tot  = base + 0.1 * cap;
        out[0] = (float)tot;
        out[1] = (float)base;
        out[2] = (float)cap;
        out[3] = 0.0f;
    }
}

extern "C" void kernel_launch(void* const* d_in, const int* in_sizes, int n_in,
                              void* d_out, int out_size, void* d_ws, size_t ws_size,
                              hipStream_t stream) {
    const float* pred = (const float*)d_in[0];
    const float* targ = (const float*)d_in[1];
    const float* Rm   = (const float*)d_in[2];
    const float* Qm   = (const float*)d_in[3];
    float* out = (float*)d_out;

    const int B = in_sizes[0] / ROW;  // 2097152

    int blocks = 2048;
    // need 2*blocks doubles of workspace
    if ((size_t)(2 * blocks) * sizeof(double) > ws_size) {
        blocks = (int)(ws_size / (2 * sizeof(double)));
        if (blocks > 2048) blocks = 2048;
        if (blocks < 1) blocks = 1;
    }

    double* partials = (double*)d_ws;

    mrta_partial_kernel<<<blocks, 256, 0, stream>>>(pred, targ, Rm, Qm, partials, B);
    mrta_final_kernel<<<1, 256, 0, stream>>>(partials, blocks, out,
                                             1.0 / ((double)B * ROW),
                                             1.0 / (double)B);
}

// Round 2
// 136.344 us; speedup vs baseline: 1.3810x; 1.3810x over previous
//
#include <hip/hip_runtime.h>

#define N_TASKS 8
#define N_ROBOTS 3
#define ROW 24  // N_TASKS * N_ROBOTS

// ---------------------------------------------------------------------------
// Stage 1: per-block partial sums of (base_loss terms, capability_violation
// terms), written as doubles to d_ws. Deterministic partition + tree.
// Softplus uses HW transcendentals (v_exp_f32 / v_log_f32 via __expf/__logf):
//   softplus(x) = max(x,0) + log(1 + exp(-|x|))
// ---------------------------------------------------------------------------
__global__ __launch_bounds__(256) void mrta_partial_kernel(
    const float* __restrict__ pred,
    const float* __restrict__ targ,
    const float* __restrict__ Rm,
    const float* __restrict__ Qm,
    double* __restrict__ partials,
    int B)
{
    const int tid      = blockIdx.x * blockDim.x + threadIdx.x;
    const int nthreads = gridDim.x * blockDim.x;

    double base_acc = 0.0;
    double cap_acc  = 0.0;

    for (int b = tid; b < B; b += nthreads) {
        float p[ROW], t[ROW], r[ROW];
        {
            const float4* pv = reinterpret_cast<const float4*>(pred + (size_t)b * ROW);
            const float4* tv = reinterpret_cast<const float4*>(targ + (size_t)b * ROW);
            const float4* rv = reinterpret_cast<const float4*>(Rm   + (size_t)b * ROW);
#pragma unroll
            for (int i = 0; i < 6; ++i) {
                float4 x = pv[i];
                p[4*i+0] = x.x; p[4*i+1] = x.y; p[4*i+2] = x.z; p[4*i+3] = x.w;
            }
#pragma unroll
            for (int i = 0; i < 6; ++i) {
                float4 x = tv[i];
                t[4*i+0] = x.x; t[4*i+1] = x.y; t[4*i+2] = x.z; t[4*i+3] = x.w;
            }
#pragma unroll
            for (int i = 0; i < 6; ++i) {
                float4 x = rv[i];
                r[4*i+0] = x.x; r[4*i+1] = x.y; r[4*i+2] = x.z; r[4*i+3] = x.w;
            }
        }

        // ---- BCE-with-logits partial: softplus(x) - x*t, HW exp/log.
        // Two independent partial sums for a bit of ILP on the trans pipe.
        float base0 = 0.0f, base1 = 0.0f;
#pragma unroll
        for (int i = 0; i < ROW; i += 2) {
            float x0 = p[i],  x1 = p[i+1];
            float e0 = __expf(-fabsf(x0));
            float e1 = __expf(-fabsf(x1));
            float sp0 = fmaxf(x0, 0.0f) + __logf(1.0f + e0);
            float sp1 = fmaxf(x1, 0.0f) + __logf(1.0f + e1);
            base0 = fmaf(-x0, t[i],   base0 + sp0);
            base1 = fmaf(-x1, t[i+1], base1 + sp1);
        }
        float base = base0 + base1;

        // ---- capability violation
        float q[9];
        {
            const float* qp = Qm + (size_t)b * 9;
#pragma unroll
            for (int i = 0; i < 9; ++i) q[i] = qp[i];
        }

        float cap = 0.0f;
#pragma unroll
        for (int tk = 0; tk < N_TASKS; ++tk) {
            float p0 = p[tk*3 + 0];
            float p1 = p[tk*3 + 1];
            float p2 = p[tk*3 + 2];
            float a0 = (p0 > 0.5f) ? 1.0f : 0.0f;
            float a1 = (p1 > 0.5f) ? 1.0f : 0.0f;
            float a2 = (p2 > 0.5f) ? 1.0f : 0.0f;
            // total_capability[c] = sum_r assigned[r] * Q[r][c]
            float tc0 = a0 * q[0] + a1 * q[3] + a2 * q[6];
            float tc1 = a0 * q[1] + a1 * q[4] + a2 * q[7];
            float tc2 = a0 * q[2] + a1 * q[5] + a2 * q[8];
            float sh  = fmaxf(r[tk*3 + 0] - tc0, 0.0f)
                      + fmaxf(r[tk*3 + 1] - tc1, 0.0f)
                      + fmaxf(r[tk*3 + 2] - tc2, 0.0f);
            bool active = (p0 + p1 + p2) > 0.0f;
            cap += active ? sh : 0.0f;
        }

        base_acc += (double)base;
        cap_acc  += (double)cap;
    }

    // ---- wave (64-lane) reduction
#pragma unroll
    for (int off = 32; off > 0; off >>= 1) {
        base_acc += __shfl_down(base_acc, off);
        cap_acc  += __shfl_down(cap_acc, off);
    }

    __shared__ double sbase[4];
    __shared__ double scap[4];
    const int wave = threadIdx.x >> 6;
    const int lane = threadIdx.x & 63;
    if (lane == 0) { sbase[wave] = base_acc; scap[wave] = cap_acc; }
    __syncthreads();
    if (threadIdx.x == 0) {
        double bsum = sbase[0] + sbase[1] + sbase[2] + sbase[3];
        double csum = scap[0]  + scap[1]  + scap[2]  + scap[3];
        partials[blockIdx.x]             = bsum;
        partials[gridDim.x + blockIdx.x] = csum;
    }
}

// ---------------------------------------------------------------------------
// Stage 2: single-block deterministic reduction + final scalar math.
// out = {total_loss, base_loss, cap_violation, 0}
// ---------------------------------------------------------------------------
__global__ __launch_bounds__(256) void mrta_final_kernel(
    const double* __restrict__ partials,
    int nparts,
    float* __restrict__ out,
    double inv_BM,   // 1 / (B * 24)
    double inv_B)    // 1 / B
{
    double b = 0.0, c = 0.0;
    for (int i = threadIdx.x; i < nparts; i += 256) {
        b += partials[i];
        c += partials[nparts + i];
    }
#pragma unroll
    for (int off = 32; off > 0; off >>= 1) {
        b += __shfl_down(b, off);
        c += __shfl_down(c, off);
    }
    __shared__ double sb[4];
    __shared__ double sc[4];
    const int wave = threadIdx.x >> 6;
    const int lane = threadIdx.x & 63;
    if (lane == 0) { sb[wave] = b; sc[wave] = c; }
    __syncthreads();
    if (threadIdx.x == 0) {
        double bsum = sb[0] + sb[1] + sb[2] + sb[3];
        double csum = sc[0] + sc[1] + sc[2] + sc[3];
        double base = bsum * inv_BM;
        double cap  = csum * inv_B;
        double tot  = base + 0.1 * cap;
        out[0] = (float)tot;
        out[1] = (float)base;
        out[2] = (float)cap;
        out[3] = 0.0f;
    }
}

extern "C" void kernel_launch(void* const* d_in, const int* in_sizes, int n_in,
                              void* d_out, int out_size, void* d_ws, size_t ws_size,
                              hipStream_t stream) {
    const float* pred = (const float*)d_in[0];
    const float* targ = (const float*)d_in[1];
    const float* Rm   = (const float*)d_in[2];
    const float* Qm   = (const float*)d_in[3];
    float* out = (float*)d_out;

    const int B = in_sizes[0] / ROW;  // 2097152

    int blocks = 2048;
    if ((size_t)(2 * blocks) * sizeof(double) > ws_size) {
        blocks = (int)(ws_size / (2 * sizeof(double)));
        if (blocks > 2048) blocks = 2048;
        if (blocks < 1) blocks = 1;
    }

    double* partials = (double*)d_ws;

    mrta_partial_kernel<<<blocks, 256, 0, stream>>>(pred, targ, Rm, Qm, partials, B);
    mrta_final_kernel<<<1, 256, 0, stream>>>(partials, blocks, out,
                                             1.0 / ((double)B * ROW),
                                             1.0 / (double)B);
}

// Round 3
// 133.387 us; speedup vs baseline: 1.4116x; 1.0222x over previous
//
#include <hip/hip_runtime.h>

#define N_TASKS 8
#define ROW 24            // floats per pred/targ/R row
#define ROWB 96           // bytes per row
#define TILE 64           // rows per wave-tile
#define QROWB 36          // bytes per Q row

typedef __attribute__((address_space(3))) void* lds_ptr_t;
typedef const __attribute__((address_space(1))) void* gbl_ptr_t;

// ---------------------------------------------------------------------------
// Stage 1: one wave (64 threads) per block, no barriers.
// Per 64-row tile:
//   - targ: 6 lane-contiguous float4 loads -> regs
//   - pred, R: 8 rounds global_load_lds(16B) each into a 128B-padded,
//     XOR-swizzled LDS tile (swizzle achieved by pre-swizzling the SOURCE
//     address; LDS dest is linear as the HW requires)
//   - Q: 3 rounds global_load_lds(16B), linear layout
//   - row phase: lane l reads row l (6 x ds_read_b128, swizzled -> ~8-way),
//     computes softplus sum + capability shortage
//   - piece phase: lane reads back its 6 pred chunks, dots with targ regs
// Accumulate in doubles, wave-shuffle reduce, one partial pair per block.
// ---------------------------------------------------------------------------
__global__ __launch_bounds__(64) void mrta_partial_kernel(
    const float* __restrict__ pred,
    const float* __restrict__ targ,
    const float* __restrict__ Rm,
    const float* __restrict__ Qm,
    double* __restrict__ partials,
    int B)
{
    __shared__ __align__(16) float4 predL[TILE * 8];  // 8 KB (6 data + 2 pad slots/row)
    __shared__ __align__(16) float4 RL[TILE * 8];     // 8 KB
    __shared__ __align__(16) float4 QL[192];          // 3 KB linear

    const int l = threadIdx.x;   // 0..63

    // --- staging source offset for pred/R (constant per lane, +768B per round)
    // dest piece d = j*64 + l -> padded (row r = d>>3, phys slot s'' = d&7).
    // phys slot s'' must hold source slot s = s'' ^ (r&7); r&7 == l>>3.
    int sfix = (l & 7) ^ (l >> 3);
    if (sfix >= 6) sfix = l & 1;                    // pad slot -> dup a valid slot (L1 hit)
    const int srcPR = ROWB * (l >> 3) + 16 * sfix;  // byte offset within 6KB source tile

    // --- piece-read LDS indices for the dot phase (constant per lane)
    int pieceIdx[6];
#pragma unroll
    for (int j = 0; j < 6; ++j) {
        int g = j * 64 + l;       // logical float4 chunk of the tile
        int r = g / 6;
        int s = g - r * 6;
        pieceIdx[j] = 8 * r + (s ^ (r & 7));
    }
    const int key = l & 7;        // row-read swizzle key for row l

    double base_acc = 0.0, cap_acc = 0.0;
    const int ntiles = B / TILE;

    for (int tile = blockIdx.x; tile < ntiles; tile += gridDim.x) {
        // single LDS buffer: prior tile's ds_reads must be complete before
        // this tile's global_load_lds can overwrite it
        asm volatile("s_waitcnt lgkmcnt(0)" ::: "memory");
        __builtin_amdgcn_sched_barrier(0);

        const char* predT = (const char*)pred + (size_t)tile * (TILE * ROWB);
        const char* targT = (const char*)targ + (size_t)tile * (TILE * ROWB);
        const char* RT    = (const char*)Rm   + (size_t)tile * (TILE * ROWB);
        const char* QT    = (const char*)Qm   + (size_t)tile * (TILE * QROWB);

        // targ -> regs, lane-contiguous
        float4 tt[6];
#pragma unroll
        for (int j = 0; j < 6; ++j)
            tt[j] = *(const float4*)(targT + (j * 64 + l) * 16);

        // pred, R -> LDS (8 rounds each, pre-swizzled source, linear dest)
#pragma unroll
        for (int j = 0; j < 8; ++j)
            __builtin_amdgcn_global_load_lds((gbl_ptr_t)(predT + j * 768 + srcPR),
                                             (lds_ptr_t)(&predL[j * 64]), 16, 0, 0);
#pragma unroll
        for (int j = 0; j < 8; ++j)
            __builtin_amdgcn_global_load_lds((gbl_ptr_t)(RT + j * 768 + srcPR),
                                             (lds_ptr_t)(&RL[j * 64]), 16, 0, 0);
        // Q -> LDS, linear (2304B valid; round 2 lanes >=16 write dup garbage into pad)
        __builtin_amdgcn_global_load_lds((gbl_ptr_t)(QT + (0 * 64 + l) * 16),
                                         (lds_ptr_t)(&QL[0]), 16, 0, 0);
        __builtin_amdgcn_global_load_lds((gbl_ptr_t)(QT + (1 * 64 + l) * 16),
                                         (lds_ptr_t)(&QL[64]), 16, 0, 0);
        __builtin_amdgcn_global_load_lds((gbl_ptr_t)(QT + 2048 + (l & 15) * 16),
                                         (lds_ptr_t)(&QL[128]), 16, 0, 0);

        asm volatile("s_waitcnt vmcnt(0)" ::: "memory");
        __builtin_amdgcn_sched_barrier(0);

        // ---- row phase: lane l owns row l of the tile ----
        float pv[ROW];
#pragma unroll
        for (int s = 0; s < 6; ++s) {
            float4 v = predL[8 * l + (s ^ key)];
            pv[4 * s + 0] = v.x; pv[4 * s + 1] = v.y;
            pv[4 * s + 2] = v.z; pv[4 * s + 3] = v.w;
        }

        float sp0 = 0.0f, sp1 = 0.0f;   // softplus sum
#pragma unroll
        for (int i = 0; i < ROW; i += 2) {
            sp0 += fmaxf(pv[i],     0.0f) + __logf(1.0f + __expf(-fabsf(pv[i])));
            sp1 += fmaxf(pv[i + 1], 0.0f) + __logf(1.0f + __expf(-fabsf(pv[i + 1])));
        }

        float rv[ROW];
#pragma unroll
        for (int s = 0; s < 6; ++s) {
            float4 v = RL[8 * l + (s ^ key)];
            rv[4 * s + 0] = v.x; rv[4 * s + 1] = v.y;
            rv[4 * s + 2] = v.z; rv[4 * s + 3] = v.w;
        }

        float qv[9];
        const float* qbase = (const float*)QL;
#pragma unroll
        for (int e = 0; e < 9; ++e) qv[e] = qbase[9 * l + e];

        float cap = 0.0f;
#pragma unroll
        for (int tk = 0; tk < N_TASKS; ++tk) {
            float p0 = pv[tk * 3 + 0];
            float p1 = pv[tk * 3 + 1];
            float p2 = pv[tk * 3 + 2];
            float a0 = (p0 > 0.5f) ? 1.0f : 0.0f;
            float a1 = (p1 > 0.5f) ? 1.0f : 0.0f;
            float a2 = (p2 > 0.5f) ? 1.0f : 0.0f;
            float tc0 = a0 * qv[0] + a1 * qv[3] + a2 * qv[6];
            float tc1 = a0 * qv[1] + a1 * qv[4] + a2 * qv[7];
            float tc2 = a0 * qv[2] + a1 * qv[5] + a2 * qv[8];
            float sh  = fmaxf(rv[tk * 3 + 0] - tc0, 0.0f)
                      + fmaxf(rv[tk * 3 + 1] - tc1, 0.0f)
                      + fmaxf(rv[tk * 3 + 2] - tc2, 0.0f);
            bool active = (p0 + p1 + p2) > 0.0f;
            cap += active ? sh : 0.0f;
        }

        // ---- piece phase: sum of p*t over this lane's 6 flat chunks ----
        float dt0 = 0.0f, dt1 = 0.0f;
#pragma unroll
        for (int j = 0; j < 6; ++j) {
            float4 pw = predL[pieceIdx[j]];
            dt0 += pw.x * tt[j].x + pw.y * tt[j].y;
            dt1 += pw.z * tt[j].z + pw.w * tt[j].w;
        }

        base_acc += (double)((sp0 + sp1) - (dt0 + dt1));
        cap_acc  += (double)cap;
    }

    // ---- tail rows (B % 64), handled scalar by block 0 ----
    if (blockIdx.x == 0) {
        int row = ntiles * TILE + l;
        if (row < B) {
            const float* pr = pred + (size_t)row * ROW;
            const float* tr = targ + (size_t)row * ROW;
            const float* rr = Rm   + (size_t)row * ROW;
            const float* qr = Qm   + (size_t)row * 9;
            float base = 0.0f;
            float pv[ROW];
            for (int i = 0; i < ROW; ++i) {
                float x = pr[i];
                pv[i] = x;
                base += fmaxf(x, 0.0f) + __logf(1.0f + __expf(-fabsf(x))) - x * tr[i];
            }
            float cap = 0.0f;
            for (int tk = 0; tk < N_TASKS; ++tk) {
                float p0 = pv[tk * 3 + 0], p1 = pv[tk * 3 + 1], p2 = pv[tk * 3 + 2];
                float a0 = (p0 > 0.5f) ? 1.0f : 0.0f;
                float a1 = (p1 > 0.5f) ? 1.0f : 0.0f;
                float a2 = (p2 > 0.5f) ? 1.0f : 0.0f;
                float tc0 = a0 * qr[0] + a1 * qr[3] + a2 * qr[6];
                float tc1 = a0 * qr[1] + a1 * qr[4] + a2 * qr[7];
                float tc2 = a0 * qr[2] + a1 * qr[5] + a2 * qr[8];
                float sh  = fmaxf(rr[tk * 3 + 0] - tc0, 0.0f)
                          + fmaxf(rr[tk * 3 + 1] - tc1, 0.0f)
                          + fmaxf(rr[tk * 3 + 2] - tc2, 0.0f);
                if ((p0 + p1 + p2) > 0.0f) cap += sh;
            }
            base_acc += (double)base;
            cap_acc  += (double)cap;
        }
    }

    // ---- wave reduction, one partial pair per block ----
#pragma unroll
    for (int off = 32; off > 0; off >>= 1) {
        base_acc += __shfl_down(base_acc, off);
        cap_acc  += __shfl_down(cap_acc, off);
    }
    if (l == 0) {
        partials[blockIdx.x]             = base_acc;
        partials[gridDim.x + blockIdx.x] = cap_acc;
    }
}

// ---------------------------------------------------------------------------
// Stage 2: single-block deterministic reduction + final scalar math.
// out = {total_loss, base_loss, cap_violation, 0}
// ---------------------------------------------------------------------------
__global__ __launch_bounds__(256) void mrta_final_kernel(
    const double* __restrict__ partials,
    int nparts,
    float* __restrict__ out,
    double inv_BM,   // 1 / (B * 24)
    double inv_B)    // 1 / B
{
    double b = 0.0, c = 0.0;
    for (int i = threadIdx.x; i < nparts; i += 256) {
        b += partials[i];
        c += partials[nparts + i];
    }
#pragma unroll
    for (int off = 32; off > 0; off >>= 1) {
        b += __shfl_down(b, off);
        c += __shfl_down(c, off);
    }
    __shared__ double sb[4];
    __shared__ double sc[4];
    const int wave = threadIdx.x >> 6;
    const int lane = threadIdx.x & 63;
    if (lane == 0) { sb[wave] = b; sc[wave] = c; }
    __syncthreads();
    if (threadIdx.x == 0) {
        double bsum = sb[0] + sb[1] + sb[2] + sb[3];
        double csum = sc[0] + sc[1] + sc[2] + sc[3];
        double base = bsum * inv_BM;
        double cap  = csum * inv_B;
        double tot  = base + 0.1 * cap;
        out[0] = (float)tot;
        out[1] = (float)base;
        out[2] = (float)cap;
        out[3] = 0.0f;
    }
}

extern "C" void kernel_launch(void* const* d_in, const int* in_sizes, int n_in,
                              void* d_out, int out_size, void* d_ws, size_t ws_size,
                              hipStream_t stream) {
    const float* pred = (const float*)d_in[0];
    const float* targ = (const float*)d_in[1];
    const float* Rm   = (const float*)d_in[2];
    const float* Qm   = (const float*)d_in[3];
    float* out = (float*)d_out;

    const int B = in_sizes[0] / ROW;  // 2097152

    int blocks = 8192;
    if ((size_t)(2 * blocks) * sizeof(double) > ws_size) {
        blocks = (int)(ws_size / (2 * sizeof(double)));
        if (blocks > 8192) blocks = 8192;
        if (blocks < 1) blocks = 1;
    }

    double* partials = (double*)d_ws;

    mrta_partial_kernel<<<blocks, 64, 0, stream>>>(pred, targ, Rm, Qm, partials, B);
    mrta_final_kernel<<<1, 256, 0, stream>>>(partials, blocks, out,
                                             1.0 / ((double)B * ROW),
                                             1.0 / (double)B);
}

// Round 4
// 124.858 us; speedup vs baseline: 1.5080x; 1.0683x over previous
//
#include <hip/hip_runtime.h>

#define N_TASKS 8
#define ROW 24            // floats per pred/targ/R row
#define ROWB 96           // bytes per row
#define TILE 64           // rows per wave-tile
#define QROWB 36          // bytes per Q row

typedef __attribute__((address_space(3))) void* lds_ptr_t;
typedef const __attribute__((address_space(1))) void* gbl_ptr_t;

// Per-buffer LDS layout (float4 indices): pred [0,512), R [512,1024), Q [1024,1168)
#define PRED0 0
#define R0    512
#define Q0    1024
#define BUFSZ 1168        // 18688 B per buffer; x2 = 37376 B -> 4 blocks/CU

#define SB0 __builtin_amdgcn_sched_barrier(0)
#define WAITV25 do { asm volatile("s_waitcnt vmcnt(25)" ::: "memory"); } while (0)
#define WAITV0  do { asm volatile("s_waitcnt vmcnt(0)"  ::: "memory"); } while (0)

// 19 global_load_lds per stage (8 pred + 8 R + 3 Q)
#define STAGE(TILEIDX, BSEL) do {                                              \
    const char* _predT = (const char*)pred + (size_t)(TILEIDX) * (TILE * ROWB);\
    const char* _RT    = (const char*)Rm   + (size_t)(TILEIDX) * (TILE * ROWB);\
    const char* _QT    = (const char*)Qm   + (size_t)(TILEIDX) * (TILE * QROWB);\
    _Pragma("unroll")                                                          \
    for (int _j = 0; _j < 8; ++_j)                                             \
        __builtin_amdgcn_global_load_lds((gbl_ptr_t)(_predT + _j * 768 + srcPR),\
                                         (lds_ptr_t)(&bufL[BSEL][PRED0 + _j * 64]), 16, 0, 0);\
    _Pragma("unroll")                                                          \
    for (int _j = 0; _j < 8; ++_j)                                             \
        __builtin_amdgcn_global_load_lds((gbl_ptr_t)(_RT + _j * 768 + srcPR),  \
                                         (lds_ptr_t)(&bufL[BSEL][R0 + _j * 64]), 16, 0, 0);\
    __builtin_amdgcn_global_load_lds((gbl_ptr_t)(_QT + l * 16),                \
                                     (lds_ptr_t)(&bufL[BSEL][Q0]), 16, 0, 0);  \
    __builtin_amdgcn_global_load_lds((gbl_ptr_t)(_QT + 1024 + l * 16),         \
                                     (lds_ptr_t)(&bufL[BSEL][Q0 + 64]), 16, 0, 0);\
    __builtin_amdgcn_global_load_lds((gbl_ptr_t)(_QT + 2048 + l * 4),          \
                                     (lds_ptr_t)(&bufL[BSEL][Q0 + 128]), 4, 0, 0);\
} while (0)

// 6 lane-contiguous float4 loads of targ into named reg array
#define LOADT(TT, TILEIDX) do {                                                \
    const char* _targT = (const char*)targ + (size_t)(TILEIDX) * (TILE * ROWB);\
    _Pragma("unroll")                                                          \
    for (int _j = 0; _j < 6; ++_j)                                             \
        TT[_j] = *(const float4*)(_targT + (_j * 64 + l) * 16);                \
} while (0)

// Full tile compute from buffer BSEL with targ regs TT
#define COMPUTE(BSEL, TT) do {                                                 \
    const float4* _predL = &bufL[BSEL][PRED0];                                 \
    const float4* _RL    = &bufL[BSEL][R0];                                    \
    const float* _qbase  = (const float*)&bufL[BSEL][Q0];                      \
    float pv[ROW];                                                             \
    _Pragma("unroll")                                                          \
    for (int _s = 0; _s < 6; ++_s) {                                           \
        float4 _v = _predL[8 * l + (_s ^ key)];                                \
        pv[4 * _s + 0] = _v.x; pv[4 * _s + 1] = _v.y;                          \
        pv[4 * _s + 2] = _v.z; pv[4 * _s + 3] = _v.w;                          \
    }                                                                          \
    float _sp0 = 0.0f, _sp1 = 0.0f;                                            \
    _Pragma("unroll")                                                          \
    for (int _i = 0; _i < ROW; _i += 2) {                                      \
        _sp0 += fmaxf(pv[_i],     0.0f) + __logf(1.0f + __expf(-fabsf(pv[_i])));\
        _sp1 += fmaxf(pv[_i + 1], 0.0f) + __logf(1.0f + __expf(-fabsf(pv[_i + 1])));\
    }                                                                          \
    float rv[ROW];                                                             \
    _Pragma("unroll")                                                          \
    for (int _s = 0; _s < 6; ++_s) {                                           \
        float4 _v = _RL[8 * l + (_s ^ key)];                                   \
        rv[4 * _s + 0] = _v.x; rv[4 * _s + 1] = _v.y;                          \
        rv[4 * _s + 2] = _v.z; rv[4 * _s + 3] = _v.w;                          \
    }                                                                          \
    float qv[9];                                                               \
    _Pragma("unroll")                                                          \
    for (int _e = 0; _e < 9; ++_e) qv[_e] = _qbase[9 * l + _e];                \
    float _cap = 0.0f;                                                         \
    _Pragma("unroll")                                                          \
    for (int _tk = 0; _tk < N_TASKS; ++_tk) {                                  \
        float _p0 = pv[_tk * 3 + 0];                                           \
        float _p1 = pv[_tk * 3 + 1];                                           \
        float _p2 = pv[_tk * 3 + 2];                                           \
        float _a0 = (_p0 > 0.5f) ? 1.0f : 0.0f;                                \
        float _a1 = (_p1 > 0.5f) ? 1.0f : 0.0f;                                \
        float _a2 = (_p2 > 0.5f) ? 1.0f : 0.0f;                                \
        float _tc0 = _a0 * qv[0] + _a1 * qv[3] + _a2 * qv[6];                  \
        float _tc1 = _a0 * qv[1] + _a1 * qv[4] + _a2 * qv[7];                  \
        float _tc2 = _a0 * qv[2] + _a1 * qv[5] + _a2 * qv[8];                  \
        float _sh  = fmaxf(rv[_tk * 3 + 0] - _tc0, 0.0f)                       \
                   + fmaxf(rv[_tk * 3 + 1] - _tc1, 0.0f)                       \
                   + fmaxf(rv[_tk * 3 + 2] - _tc2, 0.0f);                      \
        bool _active = (_p0 + _p1 + _p2) > 0.0f;                               \
        _cap += _active ? _sh : 0.0f;                                          \
    }                                                                          \
    float _dt0 = 0.0f, _dt1 = 0.0f;                                            \
    _Pragma("unroll")                                                          \
    for (int _j = 0; _j < 6; ++_j) {                                           \
        float4 _pw = _predL[pieceIdx[_j]];                                     \
        _dt0 += _pw.x * TT[_j].x + _pw.y * TT[_j].y;                           \
        _dt1 += _pw.z * TT[_j].z + _pw.w * TT[_j].w;                           \
    }                                                                          \
    base_acc += (double)((_sp0 + _sp1) - (_dt0 + _dt1));                       \
    cap_acc  += (double)_cap;                                                  \
} while (0)

// ---------------------------------------------------------------------------
// Stage 1: one wave per block, double-buffered LDS staging with counted
// vmcnt(25) (19 gll + 6 targ reg-loads per stage kept in flight under the
// previous tile's compute). No barriers; wave-private buffers.
// ---------------------------------------------------------------------------
__global__ __launch_bounds__(64) void mrta_partial_kernel(
    const float* __restrict__ pred,
    const float* __restrict__ targ,
    const float* __restrict__ Rm,
    const float* __restrict__ Qm,
    double* __restrict__ partials,
    int B)
{
    __shared__ __align__(16) float4 bufL[2][BUFSZ];

    const int l = threadIdx.x;   // 0..63

    // staging source offset (pre-swizzled so linear LDS dest yields the
    // 128B-padded XOR-swizzled tile); verified absmax 0 in R3
    int sfix = (l & 7) ^ (l >> 3);
    if (sfix >= 6) sfix = l & 1;                    // pad slot -> dup a valid slot
    const int srcPR = ROWB * (l >> 3) + 16 * sfix;

    // piece-phase LDS indices (flat chunk -> padded swizzled slot)
    int pieceIdx[6];
#pragma unroll
    for (int j = 0; j < 6; ++j) {
        int g = j * 64 + l;
        int r = g / 6;
        int s = g - r * 6;
        pieceIdx[j] = 8 * r + (s ^ (r & 7));
    }
    const int key = l & 7;

    double base_acc = 0.0, cap_acc = 0.0;

    const int G = gridDim.x;
    const int ntiles = B / TILE;
    const int t0 = blockIdx.x;
    const int n = (t0 < ntiles) ? ((ntiles - t0 + G - 1) / G) : 0;

    float4 ttA[6], ttB[6];

    if (n > 0) { STAGE(t0, 0); LOADT(ttA, t0); }

    for (int i = 0; i < n; i += 2) {
        const int tcur = t0 + i * G;
        {
            if (i + 1 < n) {
                const int tnext = tcur + G;
                STAGE(tnext, 1); LOADT(ttB, tnext);
                SB0; WAITV25; SB0;
            } else {
                SB0; WAITV0; SB0;
            }
            COMPUTE(0, ttA);
            SB0;
        }
        if (i + 1 < n) {
            if (i + 2 < n) {
                const int tnn = tcur + 2 * G;
                STAGE(tnn, 0); LOADT(ttA, tnn);
                SB0; WAITV25; SB0;
            } else {
                SB0; WAITV0; SB0;
            }
            COMPUTE(1, ttB);
            SB0;
        }
    }

    // ---- tail rows (B % 64), scalar, block 0 only ----
    if (blockIdx.x == 0) {
        int row = ntiles * TILE + l;
        if (row < B) {
            const float* pr = pred + (size_t)row * ROW;
            const float* tr = targ + (size_t)row * ROW;
            const float* rr = Rm   + (size_t)row * ROW;
            const float* qr = Qm   + (size_t)row * 9;
            float base = 0.0f;
            float pv[ROW];
            for (int i = 0; i < ROW; ++i) {
                float x = pr[i];
                pv[i] = x;
                base += fmaxf(x, 0.0f) + __logf(1.0f + __expf(-fabsf(x))) - x * tr[i];
            }
            float cap = 0.0f;
            for (int tk = 0; tk < N_TASKS; ++tk) {
                float p0 = pv[tk * 3 + 0], p1 = pv[tk * 3 + 1], p2 = pv[tk * 3 + 2];
                float a0 = (p0 > 0.5f) ? 1.0f : 0.0f;
                float a1 = (p1 > 0.5f) ? 1.0f : 0.0f;
                float a2 = (p2 > 0.5f) ? 1.0f : 0.0f;
                float tc0 = a0 * qr[0] + a1 * qr[3] + a2 * qr[6];
                float tc1 = a0 * qr[1] + a1 * qr[4] + a2 * qr[7];
                float tc2 = a0 * qr[2] + a1 * qr[5] + a2 * qr[8];
                float sh  = fmaxf(rr[tk * 3 + 0] - tc0, 0.0f)
                          + fmaxf(rr[tk * 3 + 1] - tc1, 0.0f)
                          + fmaxf(rr[tk * 3 + 2] - tc2, 0.0f);
                if ((p0 + p1 + p2) > 0.0f) cap += sh;
            }
            base_acc += (double)base;
            cap_acc  += (double)cap;
        }
    }

    // ---- wave reduction, one partial pair per block ----
#pragma unroll
    for (int off = 32; off > 0; off >>= 1) {
        base_acc += __shfl_down(base_acc, off);
        cap_acc  += __shfl_down(cap_acc, off);
    }
    if (l == 0) {
        partials[blockIdx.x]             = base_acc;
        partials[gridDim.x + blockIdx.x] = cap_acc;
    }
}

// ---------------------------------------------------------------------------
// Stage 2: single-block deterministic reduction + final scalar math.
// out = {total_loss, base_loss, cap_violation, 0}
// ---------------------------------------------------------------------------
__global__ __launch_bounds__(256) void mrta_final_kernel(
    const double* __restrict__ partials,
    int nparts,
    float* __restrict__ out,
    double inv_BM,   // 1 / (B * 24)
    double inv_B)    // 1 / B
{
    double b = 0.0, c = 0.0;
    for (int i = threadIdx.x; i < nparts; i += 256) {
        b += partials[i];
        c += partials[nparts + i];
    }
#pragma unroll
    for (int off = 32; off > 0; off >>= 1) {
        b += __shfl_down(b, off);
        c += __shfl_down(c, off);
    }
    __shared__ double sb[4];
    __shared__ double sc[4];
    const int wave = threadIdx.x >> 6;
    const int lane = threadIdx.x & 63;
    if (lane == 0) { sb[wave] = b; sc[wave] = c; }
    __syncthreads();
    if (threadIdx.x == 0) {
        double bsum = sb[0] + sb[1] + sb[2] + sb[3];
        double csum = sc[0] + sc[1] + sc[2] + sc[3];
        double base = bsum * inv_BM;
        double cap  = csum * inv_B;
        double tot  = base + 0.1 * cap;
        out[0] = (float)tot;
        out[1] = (float)base;
        out[2] = (float)cap;
        out[3] = 0.0f;
    }
}

extern "C" void kernel_launch(void* const* d_in, const int* in_sizes, int n_in,
                              void* d_out, int out_size, void* d_ws, size_t ws_size,
                              hipStream_t stream) {
    const float* pred = (const float*)d_in[0];
    const float* targ = (const float*)d_in[1];
    const float* Rm   = (const float*)d_in[2];
    const float* Qm   = (const float*)d_in[3];
    float* out = (float*)d_out;

    const int B = in_sizes[0] / ROW;  // 2097152

    int blocks = 2048;
    if ((size_t)(2 * blocks) * sizeof(double) > ws_size) {
        blocks = (int)(ws_size / (2 * sizeof(double)));
        if (blocks > 2048) blocks = 2048;
        if (blocks < 1) blocks = 1;
    }

    double* partials = (double*)d_ws;

    mrta_partial_kernel<<<blocks, 64, 0, stream>>>(pred, targ, Rm, Qm, partials, B);
    mrta_final_kernel<<<1, 256, 0, stream>>>(partials, blocks, out,
                                             1.0 / ((double)B * ROW),
                                             1.0 / (double)B);
}